// Round 1
// baseline (1893.959 us; speedup 1.0000x reference)
//
#include <hip/hip_runtime.h>

#define N_NODES 50000
#define N_EDGES 500000
#define D 128

// deg[dst] += ew  (HW fp32 atomic, no CAS loop)
__global__ void deg_kernel(const int* __restrict__ dst, const float* __restrict__ ew,
                           float* __restrict__ deg) {
    int e = blockIdx.x * blockDim.x + threadIdx.x;
    if (e < N_EDGES) unsafeAtomicAdd(&deg[dst[e]], ew[e]);
}

// deg -> dinv = rsqrt(deg + 1) in place
__global__ void dinv_kernel(float* __restrict__ deg) {
    int i = blockIdx.x * blockDim.x + threadIdx.x;
    if (i < N_NODES) deg[i] = rsqrtf(deg[i] + 1.0f);
}

// Y[N,128] = X[N,128] @ W[128,128], fp32 vector ALU.
// Block = 256 threads handles 8 rows: col = tid&127, row-group rg = tid>>7,
// each thread accumulates 4 rows (rg, rg+2, rg+4, rg+6).
__global__ void gemm_kernel(const float* __restrict__ X, const float* __restrict__ W,
                            float* __restrict__ Y) {
    __shared__ float xs[8][D];
    const int tid = threadIdx.x;
    const int row0 = blockIdx.x * 8;  // 50000 % 8 == 0, no tail
    // stage 8 rows of X (1024 floats) via float4
    const float4* Xv = (const float4*)(X + (size_t)row0 * D);
    ((float4*)&xs[0][0])[tid] = Xv[tid];
    __syncthreads();
    const int col = tid & 127;
    const int rg  = tid >> 7;
    float a0 = 0.f, a1 = 0.f, a2 = 0.f, a3 = 0.f;
#pragma unroll 8
    for (int k = 0; k < D; ++k) {
        float w = W[k * D + col];   // coalesced across 128 cols, L1/L2-hot
        a0 += xs[rg + 0][k] * w;    // LDS broadcast (same addr per row-group) — free
        a1 += xs[rg + 2][k] * w;
        a2 += xs[rg + 4][k] * w;
        a3 += xs[rg + 6][k] * w;
    }
    float* y = Y + (size_t)row0 * D + col;
    y[(rg + 0) * D] = a0;
    y[(rg + 2) * D] = a1;
    y[(rg + 4) * D] = a2;
    y[(rg + 6) * D] = a3;
}

// agg = xw * dinv^2 (self-loop) + bias   — also serves as the zero-init for the scatter
__global__ void init_agg_kernel(const float* __restrict__ xw, const float* __restrict__ dinv,
                                const float* __restrict__ b, float* __restrict__ agg) {
    int i = blockIdx.x * blockDim.x + threadIdx.x;
    if (i < N_NODES * D) {
        int node = i >> 7;
        int col  = i & 127;
        float di = dinv[node];
        agg[i] = xw[i] * di * di + b[col];
    }
}

// For each edge: agg[dst] += xw[src] * (dinv[src]*ew*dinv[dst])
// 32 threads per edge, float4 per thread (coalesced gather), 4 atomics each.
__global__ void scatter_kernel(const int* __restrict__ src, const int* __restrict__ dst,
                               const float* __restrict__ ew, const float* __restrict__ dinv,
                               const float* __restrict__ xw, float* __restrict__ agg) {
    unsigned g = blockIdx.x * blockDim.x + threadIdx.x;
    int e = g >> 5;
    int c = (g & 31) << 2;
    if (e < N_EDGES) {
        int s = src[e], d = dst[e];
        float norm = dinv[s] * ew[e] * dinv[d];
        float4 v = *(const float4*)(xw + (size_t)s * D + c);
        float* out = agg + (size_t)d * D + c;
        unsafeAtomicAdd(out + 0, v.x * norm);
        unsafeAtomicAdd(out + 1, v.y * norm);
        unsafeAtomicAdd(out + 2, v.z * norm);
        unsafeAtomicAdd(out + 3, v.w * norm);
    }
}

// out[i] = sigmoid(h[i,:] . Wf + bf) * 10 ; one wave (64 lanes) per node, 2 cols/lane
__global__ void final_kernel(const float* __restrict__ h, const float* __restrict__ Wf,
                             const float* __restrict__ bf, float* __restrict__ out) {
    int gid  = blockIdx.x * blockDim.x + threadIdx.x;
    int node = gid >> 6;
    int lane = threadIdx.x & 63;
    if (node < N_NODES) {
        const float* hr = h + (size_t)node * D;
        float a = hr[lane] * Wf[lane] + hr[64 + lane] * Wf[64 + lane];
#pragma unroll
        for (int off = 32; off > 0; off >>= 1) a += __shfl_down(a, off);
        if (lane == 0) {
            float z = a + bf[0];
            out[node] = 10.0f / (1.0f + expf(-z));
        }
    }
}

extern "C" void kernel_launch(void* const* d_in, const int* in_sizes, int n_in,
                              void* d_out, int out_size, void* d_ws, size_t ws_size,
                              hipStream_t stream) {
    const float* x  = (const float*)d_in[0];
    const int*   ei = (const int*)d_in[1];
    const float* ew = (const float*)d_in[2];
    const float* W1 = (const float*)d_in[3];
    const float* b1 = (const float*)d_in[4];
    const float* W2 = (const float*)d_in[5];
    const float* b2 = (const float*)d_in[6];
    const float* Wf = (const float*)d_in[7];
    const float* bf = (const float*)d_in[8];
    const int* srcv = ei;
    const int* dstv = ei + N_EDGES;
    float* out = (float*)d_out;

    char* ws = (char*)d_ws;
    float* dinv = (float*)ws;                                  // 50000 floats
    float* A = (float*)(ws + ((N_NODES * 4 + 255) & ~255));    // 25.6 MB: xw buffers
    float* B = A + (size_t)N_NODES * D;                        // 25.6 MB: agg/h buffers

    // degree + dinv
    hipMemsetAsync(dinv, 0, N_NODES * sizeof(float), stream);
    deg_kernel<<<(N_EDGES + 255) / 256, 256, 0, stream>>>(dstv, ew, dinv);
    dinv_kernel<<<(N_NODES + 255) / 256, 256, 0, stream>>>(dinv);

    // layer 1: A = x@W1 ; B = agg1 (= h1)
    gemm_kernel<<<N_NODES / 8, 256, 0, stream>>>(x, W1, A);
    init_agg_kernel<<<(N_NODES * D) / 256, 256, 0, stream>>>(A, dinv, b1, B);
    scatter_kernel<<<(N_EDGES * 32) / 256, 256, 0, stream>>>(srcv, dstv, ew, dinv, A, B);

    // layer 2: A = h1@W2 ; B = agg2 (= h2)  (A free after gemm consumes B)
    gemm_kernel<<<N_NODES / 8, 256, 0, stream>>>(B, W2, A);
    init_agg_kernel<<<(N_NODES * D) / 256, 256, 0, stream>>>(A, dinv, b2, B);
    scatter_kernel<<<(N_EDGES * 32) / 256, 256, 0, stream>>>(srcv, dstv, ew, dinv, A, B);

    // head
    final_kernel<<<(N_NODES * 64) / 256 + 1, 256, 0, stream>>>(B, Wf, bf, out);
}

// Round 2
// 336.440 us; speedup vs baseline: 5.6294x; 5.6294x over previous
//
#include <hip/hip_runtime.h>

#define N_NODES 50000
#define N_EDGES 500000
#define D 128

// ---- degree (weighted, for dinv) + integer histogram (for CSR) ----
__global__ void deg_cnt_kernel(const int* __restrict__ dst, const float* __restrict__ ew,
                               float* __restrict__ deg, int* __restrict__ cnt) {
    int e = blockIdx.x * blockDim.x + threadIdx.x;
    if (e < N_EDGES) {
        int d = dst[e];
        unsafeAtomicAdd(&deg[d], ew[e]);
        atomicAdd(&cnt[d], 1);
    }
}

__global__ void dinv_kernel(float* __restrict__ deg) {
    int i = blockIdx.x * blockDim.x + threadIdx.x;
    if (i < N_NODES) deg[i] = rsqrtf(deg[i] + 1.0f);
}

// ---- 3-kernel exclusive scan of cnt[50000] -> row_ptr ----
__global__ void scan1_kernel(const int* __restrict__ cnt, int* __restrict__ row_ptr,
                             int* __restrict__ bsum) {
    __shared__ int s[256];
    int t = threadIdx.x, g = blockIdx.x * 256 + t;
    int v = (g < N_NODES) ? cnt[g] : 0;
    s[t] = v;
    __syncthreads();
    for (int off = 1; off < 256; off <<= 1) {
        int add = (t >= off) ? s[t - off] : 0;
        __syncthreads();
        s[t] += add;
        __syncthreads();
    }
    if (g < N_NODES) row_ptr[g] = s[t] - v;          // exclusive within block
    if (t == 255) bsum[blockIdx.x] = s[255];         // block total
}

__global__ void scan2_kernel(int* __restrict__ bsum, int nb) {
    __shared__ int s[256];
    int t = threadIdx.x;
    int v = (t < nb) ? bsum[t] : 0;
    s[t] = v;
    __syncthreads();
    for (int off = 1; off < 256; off <<= 1) {
        int add = (t >= off) ? s[t - off] : 0;
        __syncthreads();
        s[t] += add;
        __syncthreads();
    }
    if (t < nb) bsum[t] = s[t] - v;                  // exclusive block offsets
}

__global__ void scan3_kernel(int* __restrict__ row_ptr, const int* __restrict__ bsum) {
    int g = blockIdx.x * blockDim.x + threadIdx.x;
    if (g < N_NODES) row_ptr[g] += bsum[g >> 8];
    if (g == N_NODES) row_ptr[g] = N_EDGES;
}

// ---- CSR bucket fill: pairs[idx] = (src, norm) grouped by dst ----
__global__ void csr_fill_kernel(const int* __restrict__ src, const int* __restrict__ dst,
                                const float* __restrict__ ew, const float* __restrict__ dinv,
                                const int* __restrict__ row_ptr, int* __restrict__ cursor,
                                int2* __restrict__ pairs) {
    int e = blockIdx.x * blockDim.x + threadIdx.x;
    if (e < N_EDGES) {
        int s = src[e], d = dst[e];
        float nrm = dinv[s] * ew[e] * dinv[d];
        int pos = atomicAdd(&cursor[d], 1);
        pairs[row_ptr[d] + pos] = make_int2(s, __float_as_int(nrm));
    }
}

// ---- Y[N,128] = X[N,128] @ W[128,128], fp32 vector ALU ----
__global__ void gemm_kernel(const float* __restrict__ X, const float* __restrict__ W,
                            float* __restrict__ Y) {
    __shared__ float xs[8][D];
    const int tid = threadIdx.x;
    const int row0 = blockIdx.x * 8;
    const float4* Xv = (const float4*)(X + (size_t)row0 * D);
    ((float4*)&xs[0][0])[tid] = Xv[tid];
    __syncthreads();
    const int col = tid & 127;
    const int rg  = tid >> 7;
    float a0 = 0.f, a1 = 0.f, a2 = 0.f, a3 = 0.f;
#pragma unroll 8
    for (int k = 0; k < D; ++k) {
        float w = W[k * D + col];
        a0 += xs[rg + 0][k] * w;
        a1 += xs[rg + 2][k] * w;
        a2 += xs[rg + 4][k] * w;
        a3 += xs[rg + 6][k] * w;
    }
    float* y = Y + (size_t)row0 * D + col;
    y[(rg + 0) * D] = a0;
    y[(rg + 2) * D] = a1;
    y[(rg + 4) * D] = a2;
    y[(rg + 6) * D] = a3;
}

// ---- layer-1 aggregation: one wave per node, float2 (2 cols) per lane ----
__global__ void gather1_kernel(const float* __restrict__ xw, const float* __restrict__ dinv,
                               const float* __restrict__ b, const int* __restrict__ row_ptr,
                               const int2* __restrict__ pairs, float* __restrict__ out) {
    const int lane = threadIdx.x & 63;
    const int n = blockIdx.x * 4 + (threadIdx.x >> 6);   // 50000 = 12500*4, no tail
    const float di = dinv[n];
    float2 v = ((const float2*)(xw + (size_t)n * D))[lane];
    float2 bb = ((const float2*)b)[lane];
    float2 acc;
    acc.x = v.x * di * di + bb.x;
    acc.y = v.y * di * di + bb.y;
    int i = row_ptr[n], end = row_ptr[n + 1];
    for (; i + 1 < end; i += 2) {                        // unroll-2 for load overlap
        int2 p0 = pairs[i], p1 = pairs[i + 1];
        float2 v0 = ((const float2*)(xw + (size_t)p0.x * D))[lane];
        float2 v1 = ((const float2*)(xw + (size_t)p1.x * D))[lane];
        float n0 = __int_as_float(p0.y), n1 = __int_as_float(p1.y);
        acc.x += v0.x * n0 + v1.x * n1;
        acc.y += v0.y * n0 + v1.y * n1;
    }
    if (i < end) {
        int2 p = pairs[i];
        float2 vv = ((const float2*)(xw + (size_t)p.x * D))[lane];
        float nn = __int_as_float(p.y);
        acc.x += vv.x * nn;
        acc.y += vv.y * nn;
    }
    ((float2*)(out + (size_t)n * D))[lane] = acc;
}

// ---- layer-2 aggregation fused with head: out[n] = sigmoid(h2[n]·Wf + bf)*10 ----
__global__ void gather2_head_kernel(const float* __restrict__ xw, const float* __restrict__ dinv,
                                    const float* __restrict__ b, const int* __restrict__ row_ptr,
                                    const int2* __restrict__ pairs, const float* __restrict__ Wf,
                                    const float* __restrict__ bf, float* __restrict__ out) {
    const int lane = threadIdx.x & 63;
    const int n = blockIdx.x * 4 + (threadIdx.x >> 6);
    const float di = dinv[n];
    float2 v = ((const float2*)(xw + (size_t)n * D))[lane];
    float2 bb = ((const float2*)b)[lane];
    float2 acc;
    acc.x = v.x * di * di + bb.x;
    acc.y = v.y * di * di + bb.y;
    int i = row_ptr[n], end = row_ptr[n + 1];
    for (; i + 1 < end; i += 2) {
        int2 p0 = pairs[i], p1 = pairs[i + 1];
        float2 v0 = ((const float2*)(xw + (size_t)p0.x * D))[lane];
        float2 v1 = ((const float2*)(xw + (size_t)p1.x * D))[lane];
        float n0 = __int_as_float(p0.y), n1 = __int_as_float(p1.y);
        acc.x += v0.x * n0 + v1.x * n1;
        acc.y += v0.y * n0 + v1.y * n1;
    }
    if (i < end) {
        int2 p = pairs[i];
        float2 vv = ((const float2*)(xw + (size_t)p.x * D))[lane];
        float nn = __int_as_float(p.y);
        acc.x += vv.x * nn;
        acc.y += vv.y * nn;
    }
    float2 wf = ((const float2*)Wf)[lane];
    float part = acc.x * wf.x + acc.y * wf.y;
#pragma unroll
    for (int off = 32; off > 0; off >>= 1) part += __shfl_down(part, off);
    if (lane == 0) {
        float z = part + bf[0];
        out[n] = 10.0f / (1.0f + expf(-z));
    }
}

extern "C" void kernel_launch(void* const* d_in, const int* in_sizes, int n_in,
                              void* d_out, int out_size, void* d_ws, size_t ws_size,
                              hipStream_t stream) {
    const float* x  = (const float*)d_in[0];
    const int*   ei = (const int*)d_in[1];
    const float* ew = (const float*)d_in[2];
    const float* W1 = (const float*)d_in[3];
    const float* b1 = (const float*)d_in[4];
    const float* W2 = (const float*)d_in[5];
    const float* b2 = (const float*)d_in[6];
    const float* Wf = (const float*)d_in[7];
    const float* bf = (const float*)d_in[8];
    const int* srcv = ei;
    const int* dstv = ei + N_EDGES;
    float* out = (float*)d_out;

    char* p = (char*)d_ws;
    auto alloc = [&](size_t bytes) { void* r = (void*)p; p += (bytes + 255) & ~(size_t)255; return r; };
    float* dinv   = (float*)alloc(N_NODES * 4);
    int*   cnt    = (int*)alloc(N_NODES * 4);
    int*   cursor = (int*)alloc(N_NODES * 4);
    int*   rowp   = (int*)alloc((N_NODES + 1) * 4);
    int*   bsum   = (int*)alloc(256 * 4);
    int2*  pairs  = (int2*)alloc((size_t)N_EDGES * 8);
    float* A      = (float*)alloc((size_t)N_NODES * D * 4);
    float* B      = (float*)alloc((size_t)N_NODES * D * 4);

    const int NB = (N_NODES + 255) / 256;   // 196

    hipMemsetAsync(dinv, 0, N_NODES * 4, stream);
    hipMemsetAsync(cnt, 0, N_NODES * 4, stream);
    hipMemsetAsync(cursor, 0, N_NODES * 4, stream);

    // degree + histogram + dinv
    deg_cnt_kernel<<<(N_EDGES + 255) / 256, 256, 0, stream>>>(dstv, ew, dinv, cnt);
    dinv_kernel<<<NB, 256, 0, stream>>>(dinv);

    // CSR build
    scan1_kernel<<<NB, 256, 0, stream>>>(cnt, rowp, bsum);
    scan2_kernel<<<1, 256, 0, stream>>>(bsum, NB);
    scan3_kernel<<<NB + 1, 256, 0, stream>>>(rowp, bsum);
    csr_fill_kernel<<<(N_EDGES + 255) / 256, 256, 0, stream>>>(srcv, dstv, ew, dinv, rowp, cursor, pairs);

    // layer 1: A = x@W1 ; B = aggregated h1
    gemm_kernel<<<N_NODES / 8, 256, 0, stream>>>(x, W1, A);
    gather1_kernel<<<N_NODES / 4, 256, 0, stream>>>(A, dinv, b1, rowp, pairs, B);

    // layer 2: A = h1@W2 ; fused aggregate + head -> out
    gemm_kernel<<<N_NODES / 8, 256, 0, stream>>>(B, W2, A);
    gather2_head_kernel<<<N_NODES / 4, 256, 0, stream>>>(A, dinv, b2, rowp, pairs, Wf, bf, out);
}

// Round 3
// 262.448 us; speedup vs baseline: 7.2165x; 1.2819x over previous
//
#include <hip/hip_runtime.h>
#include <hip/hip_bf16.h>

#define N_NODES 50000
#define N_EDGES 500000
#define D 128
#define FXS 4194304.0f   // 2^22 fixed-point scale for weighted degree

typedef unsigned long long u64;

// unpack 2 packed bf16 -> float2
__device__ __forceinline__ float2 bf2x(unsigned u) {
    float2 r;
    r.x = __uint_as_float(u << 16);
    r.y = __uint_as_float(u & 0xffff0000u);
    return r;
}

// ---- pass 1: one 64-bit atomic per edge: hi32 = count (returns CSR slot), lo32 = fx(ew) sum
__global__ void pass1_kernel(const int* __restrict__ dst, const float* __restrict__ ew,
                             u64* __restrict__ degcnt, int* __restrict__ epos) {
    int e = blockIdx.x * blockDim.x + threadIdx.x;
    if (e < N_EDGES) {
        int d = dst[e];
        unsigned fx = __float2uint_rn(ew[e] * FXS);
        u64 old = atomicAdd(&degcnt[d], (1ull << 32) | (u64)fx);
        epos[e] = (int)(old >> 32);
    }
}

// ---- scan stage 1: unpack degcnt -> dinv, block-scan counts ----
__global__ void scan1_kernel(const u64* __restrict__ degcnt, float* __restrict__ dinv,
                             int* __restrict__ row_ptr, int* __restrict__ bsum) {
    __shared__ int s[256];
    int t = threadIdx.x, g = blockIdx.x * 256 + t;
    int v = 0;
    if (g < N_NODES) {
        u64 dc = degcnt[g];
        v = (int)(dc >> 32);
        float deg = (float)(unsigned)(dc & 0xffffffffu) * (1.0f / FXS);
        dinv[g] = rsqrtf(deg + 1.0f);
    }
    s[t] = v;
    __syncthreads();
    for (int off = 1; off < 256; off <<= 1) {
        int add = (t >= off) ? s[t - off] : 0;
        __syncthreads();
        s[t] += add;
        __syncthreads();
    }
    if (g < N_NODES) row_ptr[g] = s[t] - v;
    if (t == 255) bsum[blockIdx.x] = s[255];
}

__global__ void scan2_kernel(int* __restrict__ bsum, int nb) {
    __shared__ int s[256];
    int t = threadIdx.x;
    int v = (t < nb) ? bsum[t] : 0;
    s[t] = v;
    __syncthreads();
    for (int off = 1; off < 256; off <<= 1) {
        int add = (t >= off) ? s[t - off] : 0;
        __syncthreads();
        s[t] += add;
        __syncthreads();
    }
    if (t < nb) bsum[t] = s[t] - v;
}

__global__ void scan3_kernel(int* __restrict__ row_ptr, const int* __restrict__ bsum) {
    int g = blockIdx.x * blockDim.x + threadIdx.x;
    if (g < N_NODES) row_ptr[g] += bsum[g >> 8];
    if (g == N_NODES) row_ptr[g] = N_EDGES;
}

// ---- CSR fill, atomic-free: slot comes from epos ----
__global__ void fill_kernel(const int* __restrict__ src, const int* __restrict__ dst,
                            const float* __restrict__ ew, const float* __restrict__ dinv,
                            const int* __restrict__ row_ptr, const int* __restrict__ epos,
                            int2* __restrict__ pairs) {
    int e = blockIdx.x * blockDim.x + threadIdx.x;
    if (e < N_EDGES) {
        int s = src[e], d = dst[e];
        float nrm = dinv[s] * ew[e] * dinv[d];
        pairs[row_ptr[d] + epos[e]] = make_int2(s, __float_as_int(nrm));
    }
}

// ---- Y[N,128] = X[N,128] @ W[128,128], fp32 math, bf16 output ----
__global__ void gemm_kernel(const float* __restrict__ X, const float* __restrict__ W,
                            __hip_bfloat16* __restrict__ Y) {
    __shared__ float xs[8][D];
    const int tid = threadIdx.x;
    const int row0 = blockIdx.x * 8;
    const float4* Xv = (const float4*)(X + (size_t)row0 * D);
    ((float4*)&xs[0][0])[tid] = Xv[tid];
    __syncthreads();
    const int col = tid & 127;
    const int rg  = tid >> 7;
    float a0 = 0.f, a1 = 0.f, a2 = 0.f, a3 = 0.f;
#pragma unroll 8
    for (int k = 0; k < D; ++k) {
        float w = W[k * D + col];
        a0 += xs[rg + 0][k] * w;
        a1 += xs[rg + 2][k] * w;
        a2 += xs[rg + 4][k] * w;
        a3 += xs[rg + 6][k] * w;
    }
    __hip_bfloat16* y = Y + (size_t)row0 * D + col;
    y[(rg + 0) * D] = __float2bfloat16(a0);
    y[(rg + 2) * D] = __float2bfloat16(a1);
    y[(rg + 4) * D] = __float2bfloat16(a2);
    y[(rg + 6) * D] = __float2bfloat16(a3);
}

// ---- layer-1 aggregation: one wave per node, 2 bf16 cols per lane (4B loads) ----
__global__ void gather1_kernel(const unsigned* __restrict__ xw, const float* __restrict__ dinv,
                               const float* __restrict__ b, const int* __restrict__ row_ptr,
                               const int2* __restrict__ pairs, float* __restrict__ out) {
    const int lane = threadIdx.x & 63;
    const int n = blockIdx.x * 4 + (threadIdx.x >> 6);   // 50000 = 12500*4
    const float di = dinv[n];
    float2 sl = bf2x(xw[n * 64 + lane]);
    float2 bb = ((const float2*)b)[lane];
    float2 acc;
    acc.x = sl.x * di * di + bb.x;
    acc.y = sl.y * di * di + bb.y;
    int i = row_ptr[n], end = row_ptr[n + 1];
    for (; i + 3 < end; i += 4) {
        int2 p0 = pairs[i], p1 = pairs[i + 1], p2 = pairs[i + 2], p3 = pairs[i + 3];
        unsigned u0 = xw[p0.x * 64 + lane];
        unsigned u1 = xw[p1.x * 64 + lane];
        unsigned u2 = xw[p2.x * 64 + lane];
        unsigned u3 = xw[p3.x * 64 + lane];
        float2 v0 = bf2x(u0), v1 = bf2x(u1), v2 = bf2x(u2), v3 = bf2x(u3);
        float n0 = __int_as_float(p0.y), n1 = __int_as_float(p1.y);
        float n2 = __int_as_float(p2.y), n3 = __int_as_float(p3.y);
        acc.x += v0.x * n0 + v1.x * n1 + v2.x * n2 + v3.x * n3;
        acc.y += v0.y * n0 + v1.y * n1 + v2.y * n2 + v3.y * n3;
    }
    for (; i < end; ++i) {
        int2 p = pairs[i];
        float2 vv = bf2x(xw[p.x * 64 + lane]);
        float nn = __int_as_float(p.y);
        acc.x += vv.x * nn;
        acc.y += vv.y * nn;
    }
    ((float2*)(out + (size_t)n * D))[lane] = acc;
}

// ---- layer-2 aggregation fused with head ----
__global__ void gather2_head_kernel(const unsigned* __restrict__ xw, const float* __restrict__ dinv,
                                    const float* __restrict__ b, const int* __restrict__ row_ptr,
                                    const int2* __restrict__ pairs, const float* __restrict__ Wf,
                                    const float* __restrict__ bf, float* __restrict__ out) {
    const int lane = threadIdx.x & 63;
    const int n = blockIdx.x * 4 + (threadIdx.x >> 6);
    const float di = dinv[n];
    float2 sl = bf2x(xw[n * 64 + lane]);
    float2 bb = ((const float2*)b)[lane];
    float2 acc;
    acc.x = sl.x * di * di + bb.x;
    acc.y = sl.y * di * di + bb.y;
    int i = row_ptr[n], end = row_ptr[n + 1];
    for (; i + 3 < end; i += 4) {
        int2 p0 = pairs[i], p1 = pairs[i + 1], p2 = pairs[i + 2], p3 = pairs[i + 3];
        unsigned u0 = xw[p0.x * 64 + lane];
        unsigned u1 = xw[p1.x * 64 + lane];
        unsigned u2 = xw[p2.x * 64 + lane];
        unsigned u3 = xw[p3.x * 64 + lane];
        float2 v0 = bf2x(u0), v1 = bf2x(u1), v2 = bf2x(u2), v3 = bf2x(u3);
        float n0 = __int_as_float(p0.y), n1 = __int_as_float(p1.y);
        float n2 = __int_as_float(p2.y), n3 = __int_as_float(p3.y);
        acc.x += v0.x * n0 + v1.x * n1 + v2.x * n2 + v3.x * n3;
        acc.y += v0.y * n0 + v1.y * n1 + v2.y * n2 + v3.y * n3;
    }
    for (; i < end; ++i) {
        int2 p = pairs[i];
        float2 vv = bf2x(xw[p.x * 64 + lane]);
        float nn = __int_as_float(p.y);
        acc.x += vv.x * nn;
        acc.y += vv.y * nn;
    }
    float2 wf = ((const float2*)Wf)[lane];
    float part = acc.x * wf.x + acc.y * wf.y;
#pragma unroll
    for (int off = 32; off > 0; off >>= 1) part += __shfl_down(part, off);
    if (lane == 0) {
        float z = part + bf[0];
        out[n] = 10.0f / (1.0f + expf(-z));
    }
}

extern "C" void kernel_launch(void* const* d_in, const int* in_sizes, int n_in,
                              void* d_out, int out_size, void* d_ws, size_t ws_size,
                              hipStream_t stream) {
    const float* x  = (const float*)d_in[0];
    const int*   ei = (const int*)d_in[1];
    const float* ew = (const float*)d_in[2];
    const float* W1 = (const float*)d_in[3];
    const float* b1 = (const float*)d_in[4];
    const float* W2 = (const float*)d_in[5];
    const float* b2 = (const float*)d_in[6];
    const float* Wf = (const float*)d_in[7];
    const float* bf = (const float*)d_in[8];
    const int* srcv = ei;
    const int* dstv = ei + N_EDGES;
    float* out = (float*)d_out;

    char* p = (char*)d_ws;
    auto alloc = [&](size_t bytes) { void* r = (void*)p; p += (bytes + 255) & ~(size_t)255; return r; };
    u64*   degcnt = (u64*)alloc((size_t)N_NODES * 8);
    float* dinv   = (float*)alloc(N_NODES * 4);
    int*   rowp   = (int*)alloc((N_NODES + 1) * 4);
    int*   bsum   = (int*)alloc(256 * 4);
    int*   epos   = (int*)alloc((size_t)N_EDGES * 4);
    int2*  pairs  = (int2*)alloc((size_t)N_EDGES * 8);
    __hip_bfloat16* A = (__hip_bfloat16*)alloc((size_t)N_NODES * D * 2);  // bf16 xw
    float* B      = (float*)alloc((size_t)N_NODES * D * 4);               // fp32 h1

    const int NB = (N_NODES + 255) / 256;   // 196
    const int EB = (N_EDGES + 255) / 256;

    hipMemsetAsync(degcnt, 0, (size_t)N_NODES * 8, stream);

    // one packed atomic per edge; returned count = CSR slot
    pass1_kernel<<<EB, 256, 0, stream>>>(dstv, ew, degcnt, epos);
    // scan counts -> rowp, unpack deg -> dinv
    scan1_kernel<<<NB, 256, 0, stream>>>(degcnt, dinv, rowp, bsum);
    scan2_kernel<<<1, 256, 0, stream>>>(bsum, NB);
    scan3_kernel<<<NB + 1, 256, 0, stream>>>(rowp, bsum);
    // atomic-free CSR fill with precomputed norms
    fill_kernel<<<EB, 256, 0, stream>>>(srcv, dstv, ew, dinv, rowp, epos, pairs);

    // layer 1: A(bf16) = x@W1 ; B(fp32) = aggregated h1
    gemm_kernel<<<N_NODES / 8, 256, 0, stream>>>(x, W1, A);
    gather1_kernel<<<N_NODES / 4, 256, 0, stream>>>((const unsigned*)A, dinv, b1, rowp, pairs, B);

    // layer 2: A(bf16) = h1@W2 ; fused aggregate + head -> out
    gemm_kernel<<<N_NODES / 8, 256, 0, stream>>>(B, W2, A);
    gather2_head_kernel<<<N_NODES / 4, 256, 0, stream>>>((const unsigned*)A, dinv, b2, rowp, pairs, Wf, bf, out);
}

// Round 4
// 211.471 us; speedup vs baseline: 8.9561x; 1.2411x over previous
//
#include <hip/hip_runtime.h>

#define N_NODES 50000
#define N_EDGES 500000
#define D 128
#define FXS 4194304.0f   // 2^22 fixed-point scale for weighted degree

typedef unsigned long long u64;
typedef unsigned int uint;
typedef short short8 __attribute__((ext_vector_type(8)));
typedef float f32x4 __attribute__((ext_vector_type(4)));

// round-to-nearest-even fp32 -> bf16 bits
__device__ __forceinline__ unsigned short bfr(float f) {
    unsigned u = __float_as_uint(f);
    return (unsigned short)((u + 0x7fffu + ((u >> 16) & 1u)) >> 16);
}

// unpack 2 packed bf16 -> float2
__device__ __forceinline__ float2 bf2x(uint u) {
    float2 r;
    r.x = __uint_as_float(u << 16);
    r.y = __uint_as_float(u & 0xffff0000u);
    return r;
}

// ---- pass 1: one 64-bit atomic per edge: hi32 = count (returns CSR slot), lo32 = fx(ew) sum
__global__ void pass1_kernel(const int* __restrict__ dst, const float* __restrict__ ew,
                             u64* __restrict__ degcnt, int* __restrict__ epos) {
    int e = blockIdx.x * blockDim.x + threadIdx.x;
    if (e < N_EDGES) {
        int d = dst[e];
        unsigned fx = __float2uint_rn(ew[e] * FXS);
        u64 old = atomicAdd(&degcnt[d], (1ull << 32) | (u64)fx);
        epos[e] = (int)(old >> 32);
    }
}

// ---- scan stage 1: unpack degcnt -> dinv, block-scan counts ----
__global__ void scan1_kernel(const u64* __restrict__ degcnt, float* __restrict__ dinv,
                             int* __restrict__ row_ptr, int* __restrict__ bsum) {
    __shared__ int s[256];
    int t = threadIdx.x, g = blockIdx.x * 256 + t;
    int v = 0;
    if (g < N_NODES) {
        u64 dc = degcnt[g];
        v = (int)(dc >> 32);
        float deg = (float)(unsigned)(dc & 0xffffffffu) * (1.0f / FXS);
        dinv[g] = rsqrtf(deg + 1.0f);
    }
    s[t] = v;
    __syncthreads();
    for (int off = 1; off < 256; off <<= 1) {
        int add = (t >= off) ? s[t - off] : 0;
        __syncthreads();
        s[t] += add;
        __syncthreads();
    }
    if (g < N_NODES) row_ptr[g] = s[t] - v;
    if (t == 255) bsum[blockIdx.x] = s[255];
}

__global__ void scan2_kernel(int* __restrict__ bsum, int nb) {
    __shared__ int s[256];
    int t = threadIdx.x;
    int v = (t < nb) ? bsum[t] : 0;
    s[t] = v;
    __syncthreads();
    for (int off = 1; off < 256; off <<= 1) {
        int add = (t >= off) ? s[t - off] : 0;
        __syncthreads();
        s[t] += add;
        __syncthreads();
    }
    if (t < nb) bsum[t] = s[t] - v;
}

__global__ void scan3_kernel(int* __restrict__ row_ptr, const int* __restrict__ bsum) {
    int g = blockIdx.x * blockDim.x + threadIdx.x;
    if (g < N_NODES) row_ptr[g] += bsum[g >> 8];
    if (g == N_NODES) row_ptr[g] = N_EDGES;
}

// ---- CSR fill, atomic-free: slot comes from epos ----
__global__ void fill_kernel(const int* __restrict__ src, const int* __restrict__ dst,
                            const float* __restrict__ ew, const float* __restrict__ dinv,
                            const int* __restrict__ row_ptr, const int* __restrict__ epos,
                            int2* __restrict__ pairs) {
    int e = blockIdx.x * blockDim.x + threadIdx.x;
    if (e < N_EDGES) {
        int s = src[e], d = dst[e];
        float nrm = dinv[s] * ew[e] * dinv[d];
        pairs[row_ptr[d] + epos[e]] = make_int2(s, __float_as_int(nrm));
    }
}

// ---- pack W (128x128 fp32, row-major K x N) into MFMA B-fragment layout, bf16 ----
// Wp index: ((t*4 + s)*64 + lane)*8 + j  holds  W[s*32 + (lane>>4)*8 + j][t*16 + (lane&15)]
// blocks 0..7 pack W1 -> Wp1, blocks 8..15 pack W2 -> Wp2
__global__ void pack_kernel(const float* __restrict__ Wa, unsigned short* __restrict__ Wpa,
                            const float* __restrict__ Wb, unsigned short* __restrict__ Wpb) {
    int blk = blockIdx.x;
    const float* W = (blk < 8) ? Wa : Wb;
    unsigned short* Wp = (blk < 8) ? Wpa : Wpb;
    int id = (blk & 7) * 256 + threadIdx.x;   // 2048 entries of 8
    int l = id & 63, s = (id >> 6) & 3, t = id >> 8;
    int k0 = s * 32 + ((l >> 4) << 3);
    int n = t * 16 + (l & 15);
    unsigned short* o = Wp + (size_t)id * 8;
#pragma unroll
    for (int j = 0; j < 8; ++j) o[j] = bfr(W[(k0 + j) * D + n]);
}

// ---- MFMA GEMM: Y[N,128](bf16) = X[N,128](fp32) @ W (pre-packed bf16 frags) ----
// block = 256 (4 waves), each wave computes 16 rows x 128 cols
__global__ void mfma_gemm_kernel(const float* __restrict__ X, const short8* __restrict__ Wp,
                                 unsigned short* __restrict__ Y) {
    const int tid = threadIdx.x;
    const int wave = tid >> 6, lane = tid & 63;
    const int row0 = (blockIdx.x * 4 + wave) * 16;
    const int m = lane & 15, g = lane >> 4;
    int lrow = row0 + m;
    if (lrow >= N_NODES) lrow = N_NODES - 1;   // clamp (duplicate) for loads
    const float* xr = X + (size_t)lrow * D + g * 8;

    f32x4 acc[8];
#pragma unroll
    for (int t = 0; t < 8; ++t) acc[t] = (f32x4)(0.0f);

#pragma unroll
    for (int s = 0; s < 4; ++s) {
        float4 a0 = *(const float4*)(xr + s * 32);
        float4 a1 = *(const float4*)(xr + s * 32 + 4);
        short8 af;
        af[0] = (short)bfr(a0.x); af[1] = (short)bfr(a0.y);
        af[2] = (short)bfr(a0.z); af[3] = (short)bfr(a0.w);
        af[4] = (short)bfr(a1.x); af[5] = (short)bfr(a1.y);
        af[6] = (short)bfr(a1.z); af[7] = (short)bfr(a1.w);
#pragma unroll
        for (int t = 0; t < 8; ++t) {
            short8 bfrag = Wp[(t * 4 + s) * 64 + lane];
            acc[t] = __builtin_amdgcn_mfma_f32_16x16x32_bf16(af, bfrag, acc[t], 0, 0, 0);
        }
    }
    // C/D: col = t*16 + (lane&15), row = row0 + (lane>>4)*4 + r
#pragma unroll
    for (int r = 0; r < 4; ++r) {
        int rw = row0 + g * 4 + r;
        if (rw < N_NODES) {
            unsigned short* y = Y + (size_t)rw * D + m;
#pragma unroll
            for (int t = 0; t < 8; ++t) y[t * 16] = bfr(acc[t][r]);
        }
    }
}

// ---- layer-1 aggregation: one wave per node; 16 lanes x uint4 (8 bf16 cols) per row,
// 4 edge-subgroups round-robin, butterfly-combined. out fp32.
__global__ void gather1_kernel(const uint* __restrict__ xw, const float* __restrict__ dinv,
                               const float* __restrict__ b, const int* __restrict__ row_ptr,
                               const int2* __restrict__ pairs, float* __restrict__ out) {
    const int tid = threadIdx.x;
    const int lane = tid & 63, sub = lane >> 4, cl = lane & 15;
    const int n = blockIdx.x * 4 + (tid >> 6);   // 50000 = 12500*4
    float a0 = 0.f, a1 = 0.f, a2 = 0.f, a3 = 0.f, a4 = 0.f, a5 = 0.f, a6 = 0.f, a7 = 0.f;
    if (sub == 0) {
        float di = dinv[n];
        float d2 = di * di;
        uint4 sv = *(const uint4*)(xw + (size_t)n * 64 + cl * 4);
        float2 v0 = bf2x(sv.x), v1 = bf2x(sv.y), v2 = bf2x(sv.z), v3 = bf2x(sv.w);
        float4 bA = *(const float4*)(b + cl * 8);
        float4 bB = *(const float4*)(b + cl * 8 + 4);
        a0 = v0.x * d2 + bA.x; a1 = v0.y * d2 + bA.y;
        a2 = v1.x * d2 + bA.z; a3 = v1.y * d2 + bA.w;
        a4 = v2.x * d2 + bB.x; a5 = v2.y * d2 + bB.y;
        a6 = v3.x * d2 + bB.z; a7 = v3.y * d2 + bB.w;
    }
    int i = row_ptr[n] + sub, end = row_ptr[n + 1];
    for (; i < end; i += 4) {
        int2 p = pairs[i];
        float nn = __int_as_float(p.y);
        uint4 rv = *(const uint4*)(xw + (size_t)p.x * 64 + cl * 4);
        float2 v0 = bf2x(rv.x), v1 = bf2x(rv.y), v2 = bf2x(rv.z), v3 = bf2x(rv.w);
        a0 += v0.x * nn; a1 += v0.y * nn; a2 += v1.x * nn; a3 += v1.y * nn;
        a4 += v2.x * nn; a5 += v2.y * nn; a6 += v3.x * nn; a7 += v3.y * nn;
    }
    a0 += __shfl_xor(a0, 16); a1 += __shfl_xor(a1, 16);
    a2 += __shfl_xor(a2, 16); a3 += __shfl_xor(a3, 16);
    a4 += __shfl_xor(a4, 16); a5 += __shfl_xor(a5, 16);
    a6 += __shfl_xor(a6, 16); a7 += __shfl_xor(a7, 16);
    a0 += __shfl_xor(a0, 32); a1 += __shfl_xor(a1, 32);
    a2 += __shfl_xor(a2, 32); a3 += __shfl_xor(a3, 32);
    a4 += __shfl_xor(a4, 32); a5 += __shfl_xor(a5, 32);
    a6 += __shfl_xor(a6, 32); a7 += __shfl_xor(a7, 32);
    if (sub == 0) {
        float* o = out + (size_t)n * D + cl * 8;
        *(float4*)o = make_float4(a0, a1, a2, a3);
        *(float4*)(o + 4) = make_float4(a4, a5, a6, a7);
    }
}

// ---- layer-2 aggregation fused with head: out[n] = sigmoid(h2[n]·Wf + bf)*10 ----
__global__ void gather2_head_kernel(const uint* __restrict__ xw, const float* __restrict__ dinv,
                                    const float* __restrict__ b, const int* __restrict__ row_ptr,
                                    const int2* __restrict__ pairs, const float* __restrict__ Wf,
                                    const float* __restrict__ bf, float* __restrict__ out) {
    const int tid = threadIdx.x;
    const int lane = tid & 63, sub = lane >> 4, cl = lane & 15;
    const int n = blockIdx.x * 4 + (tid >> 6);
    float a0 = 0.f, a1 = 0.f, a2 = 0.f, a3 = 0.f, a4 = 0.f, a5 = 0.f, a6 = 0.f, a7 = 0.f;
    if (sub == 0) {
        float di = dinv[n];
        float d2 = di * di;
        uint4 sv = *(const uint4*)(xw + (size_t)n * 64 + cl * 4);
        float2 v0 = bf2x(sv.x), v1 = bf2x(sv.y), v2 = bf2x(sv.z), v3 = bf2x(sv.w);
        float4 bA = *(const float4*)(b + cl * 8);
        float4 bB = *(const float4*)(b + cl * 8 + 4);
        a0 = v0.x * d2 + bA.x; a1 = v0.y * d2 + bA.y;
        a2 = v1.x * d2 + bA.z; a3 = v1.y * d2 + bA.w;
        a4 = v2.x * d2 + bB.x; a5 = v2.y * d2 + bB.y;
        a6 = v3.x * d2 + bB.z; a7 = v3.y * d2 + bB.w;
    }
    int i = row_ptr[n] + sub, end = row_ptr[n + 1];
    for (; i < end; i += 4) {
        int2 p = pairs[i];
        float nn = __int_as_float(p.y);
        uint4 rv = *(const uint4*)(xw + (size_t)p.x * 64 + cl * 4);
        float2 v0 = bf2x(rv.x), v1 = bf2x(rv.y), v2 = bf2x(rv.z), v3 = bf2x(rv.w);
        a0 += v0.x * nn; a1 += v0.y * nn; a2 += v1.x * nn; a3 += v1.y * nn;
        a4 += v2.x * nn; a5 += v2.y * nn; a6 += v3.x * nn; a7 += v3.y * nn;
    }
    a0 += __shfl_xor(a0, 16); a1 += __shfl_xor(a1, 16);
    a2 += __shfl_xor(a2, 16); a3 += __shfl_xor(a3, 16);
    a4 += __shfl_xor(a4, 16); a5 += __shfl_xor(a5, 16);
    a6 += __shfl_xor(a6, 16); a7 += __shfl_xor(a7, 16);
    a0 += __shfl_xor(a0, 32); a1 += __shfl_xor(a1, 32);
    a2 += __shfl_xor(a2, 32); a3 += __shfl_xor(a3, 32);
    a4 += __shfl_xor(a4, 32); a5 += __shfl_xor(a5, 32);
    a6 += __shfl_xor(a6, 32); a7 += __shfl_xor(a7, 32);
    // all lanes now hold full sums for their 8 cols; dot with Wf
    float4 wA = *(const float4*)(Wf + cl * 8);
    float4 wB = *(const float4*)(Wf + cl * 8 + 4);
    float part = a0 * wA.x + a1 * wA.y + a2 * wA.z + a3 * wA.w +
                 a4 * wB.x + a5 * wB.y + a6 * wB.z + a7 * wB.w;
    part += __shfl_xor(part, 1);
    part += __shfl_xor(part, 2);
    part += __shfl_xor(part, 4);
    part += __shfl_xor(part, 8);
    if (lane == 0) {
        float z = part + bf[0];
        out[n] = 10.0f / (1.0f + expf(-z));
    }
}

extern "C" void kernel_launch(void* const* d_in, const int* in_sizes, int n_in,
                              void* d_out, int out_size, void* d_ws, size_t ws_size,
                              hipStream_t stream) {
    const float* x  = (const float*)d_in[0];
    const int*   ei = (const int*)d_in[1];
    const float* ew = (const float*)d_in[2];
    const float* W1 = (const float*)d_in[3];
    const float* b1 = (const float*)d_in[4];
    const float* W2 = (const float*)d_in[5];
    const float* b2 = (const float*)d_in[6];
    const float* Wf = (const float*)d_in[7];
    const float* bf = (const float*)d_in[8];
    const int* srcv = ei;
    const int* dstv = ei + N_EDGES;
    float* out = (float*)d_out;

    char* p = (char*)d_ws;
    auto alloc = [&](size_t bytes) { void* r = (void*)p; p += (bytes + 255) & ~(size_t)255; return r; };
    u64*   degcnt = (u64*)alloc((size_t)N_NODES * 8);
    float* dinv   = (float*)alloc(N_NODES * 4);
    int*   rowp   = (int*)alloc((N_NODES + 1) * 4);
    int*   bsum   = (int*)alloc(256 * 4);
    int*   epos   = (int*)alloc((size_t)N_EDGES * 4);
    int2*  pairs  = (int2*)alloc((size_t)N_EDGES * 8);
    unsigned short* Wp1 = (unsigned short*)alloc((size_t)D * D * 2);
    unsigned short* Wp2 = (unsigned short*)alloc((size_t)D * D * 2);
    unsigned short* A = (unsigned short*)alloc((size_t)N_NODES * D * 2);  // bf16 xw
    float* B      = (float*)alloc((size_t)N_NODES * D * 4);               // fp32 h1

    const int NB = (N_NODES + 255) / 256;   // 196
    const int EB = (N_EDGES + 255) / 256;
    const int GB = (N_NODES + 63) / 64;     // 782 gemm blocks (4 waves x 16 rows)

    hipMemsetAsync(degcnt, 0, (size_t)N_NODES * 8, stream);

    // pack both weight matrices into MFMA B-frag layout
    pack_kernel<<<16, 256, 0, stream>>>(W1, Wp1, W2, Wp2);

    // one packed atomic per edge; returned count = CSR slot
    pass1_kernel<<<EB, 256, 0, stream>>>(dstv, ew, degcnt, epos);
    // scan counts -> rowp, unpack deg -> dinv
    scan1_kernel<<<NB, 256, 0, stream>>>(degcnt, dinv, rowp, bsum);
    scan2_kernel<<<1, 256, 0, stream>>>(bsum, NB);
    scan3_kernel<<<NB + 1, 256, 0, stream>>>(rowp, bsum);
    // atomic-free CSR fill with precomputed norms
    fill_kernel<<<EB, 256, 0, stream>>>(srcv, dstv, ew, dinv, rowp, epos, pairs);

    // layer 1: A(bf16) = x@W1 ; B(fp32) = aggregated h1
    mfma_gemm_kernel<<<GB, 256, 0, stream>>>(x, (const short8*)Wp1, A);
    gather1_kernel<<<N_NODES / 4, 256, 0, stream>>>((const uint*)A, dinv, b1, rowp, pairs, B);

    // layer 2: A(bf16) = h1@W2 ; fused aggregate + head -> out
    mfma_gemm_kernel<<<GB, 256, 0, stream>>>(B, (const short8*)Wp2, A);
    gather2_head_kernel<<<N_NODES / 4, 256, 0, stream>>>((const uint*)A, dinv, b2, rowp, pairs, Wf, bf, out);
}

// Round 5
// 155.413 us; speedup vs baseline: 12.1867x; 1.3607x over previous
//
#include <hip/hip_runtime.h>

#define N_NODES 50000
#define N_EDGES 500000
#define D 128
#define FXS 4194304.0f   // 2^22 fixed-point scale for weighted degree

typedef unsigned long long u64;

// ---- pass 1: one 64-bit atomic per edge: hi32 = count (returns CSR slot), lo32 = fx(ew) sum
__global__ void pass1_kernel(const int* __restrict__ dst, const float* __restrict__ ew,
                             u64* __restrict__ degcnt, int* __restrict__ epos) {
    int e = blockIdx.x * blockDim.x + threadIdx.x;
    if (e < N_EDGES) {
        int d = dst[e];
        unsigned fx = __float2uint_rn(ew[e] * FXS);
        u64 old = atomicAdd(&degcnt[d], (1ull << 32) | (u64)fx);
        epos[e] = (int)(old >> 32);
    }
}

// ---- scan stage 1: unpack degcnt -> dinv, block-scan counts ----
__global__ void scan1_kernel(const u64* __restrict__ degcnt, float* __restrict__ dinv,
                             int* __restrict__ row_ptr, int* __restrict__ bsum) {
    __shared__ int s[256];
    int t = threadIdx.x, g = blockIdx.x * 256 + t;
    int v = 0;
    if (g < N_NODES) {
        u64 dc = degcnt[g];
        v = (int)(dc >> 32);
        float deg = (float)(unsigned)(dc & 0xffffffffu) * (1.0f / FXS);
        dinv[g] = rsqrtf(deg + 1.0f);
    }
    s[t] = v;
    __syncthreads();
    for (int off = 1; off < 256; off <<= 1) {
        int add = (t >= off) ? s[t - off] : 0;
        __syncthreads();
        s[t] += add;
        __syncthreads();
    }
    if (g < N_NODES) row_ptr[g] = s[t] - v;
    if (t == 255) bsum[blockIdx.x] = s[255];
}

__global__ void scan2_kernel(int* __restrict__ bsum, int nb) {
    __shared__ int s[256];
    int t = threadIdx.x;
    int v = (t < nb) ? bsum[t] : 0;
    s[t] = v;
    __syncthreads();
    for (int off = 1; off < 256; off <<= 1) {
        int add = (t >= off) ? s[t - off] : 0;
        __syncthreads();
        s[t] += add;
        __syncthreads();
    }
    if (t < nb) bsum[t] = s[t] - v;
}

__global__ void scan3_kernel(int* __restrict__ row_ptr, const int* __restrict__ bsum) {
    int g = blockIdx.x * blockDim.x + threadIdx.x;
    if (g < N_NODES) row_ptr[g] += bsum[g >> 8];
    if (g == N_NODES) row_ptr[g] = N_EDGES;
}

// ---- CSR fill, atomic-free: slot comes from epos ----
__global__ void fill_kernel(const int* __restrict__ src, const int* __restrict__ dst,
                            const float* __restrict__ ew, const float* __restrict__ dinv,
                            const int* __restrict__ row_ptr, const int* __restrict__ epos,
                            int2* __restrict__ pairs) {
    int e = blockIdx.x * blockDim.x + threadIdx.x;
    if (e < N_EDGES) {
        int s = src[e], d = dst[e];
        float nrm = dinv[s] * ew[e] * dinv[d];
        pairs[row_ptr[d] + epos[e]] = make_int2(s, __float_as_int(nrm));
    }
}

// ---- collapse the linear net: v = W1 @ (W2 @ Wf), c1 = b1.(W2@Wf), c0 = b2.Wf + bf ----
__global__ void precompute_kernel(const float* __restrict__ W1, const float* __restrict__ W2,
                                  const float* __restrict__ b1, const float* __restrict__ b2,
                                  const float* __restrict__ Wf, const float* __restrict__ bf,
                                  float* __restrict__ v, float* __restrict__ consts) {
    __shared__ float u[D];
    int t = threadIdx.x;   // 128 threads
    float acc = 0.f;
#pragma unroll 8
    for (int j = 0; j < D; ++j) acc += W2[t * D + j] * Wf[j];
    u[t] = acc;
    __syncthreads();
    float vv = 0.f;
#pragma unroll 8
    for (int k = 0; k < D; ++k) vv += W1[t * D + k] * u[k];
    v[t] = vv;
    if (t == 0) {
        float c1 = 0.f;
        for (int k = 0; k < D; ++k) c1 += b1[k] * u[k];
        consts[0] = c1;
    } else if (t == 1) {
        float c0 = bf[0];
        for (int k = 0; k < D; ++k) c0 += b2[k] * Wf[k];
        consts[1] = c0;
    }
}

// ---- t[n] = x[n,:] . v   (one wave per node, float2 per lane) ----
__global__ void gemv_kernel(const float* __restrict__ x, const float* __restrict__ v,
                            float* __restrict__ tv) {
    __shared__ float vs[D];
    int tid = threadIdx.x;
    if (tid < D) vs[tid] = v[tid];
    __syncthreads();
    int lane = tid & 63;
    int n = blockIdx.x * 4 + (tid >> 6);   // 50000 = 12500*4
    float2 xv = ((const float2*)(x + (size_t)n * D))[lane];
    float a = xv.x * vs[lane * 2] + xv.y * vs[lane * 2 + 1];
#pragma unroll
    for (int off = 32; off > 0; off >>= 1) a += __shfl_xor(a, off);
    if (lane == 0) tv[n] = a;
}

// ---- s[n] = sum norm * t[src] + dinv[n]^2 * t[n] + c1   (8 lanes per node) ----
__global__ void gather_s_kernel(const float* __restrict__ tv, const float* __restrict__ dinv,
                                const int* __restrict__ row_ptr, const int2* __restrict__ pairs,
                                const float* __restrict__ consts, float* __restrict__ sv) {
    int tid = threadIdx.x;
    int n = blockIdx.x * 32 + (tid >> 3);
    int l = tid & 7;
    if (n >= N_NODES) return;
    float acc = 0.f;
    int i = row_ptr[n] + l, end = row_ptr[n + 1];
    for (; i < end; i += 8) {
        int2 p = pairs[i];
        acc += __int_as_float(p.y) * tv[p.x];
    }
    acc += __shfl_xor(acc, 1);
    acc += __shfl_xor(acc, 2);
    acc += __shfl_xor(acc, 4);
    if (l == 0) {
        float di = dinv[n];
        sv[n] = acc + di * di * tv[n] + consts[0];
    }
}

// ---- out[n] = sigmoid( sum norm * s[src] + dinv[n]^2 * s[n] + c0 ) * 10 ----
__global__ void gather_z_kernel(const float* __restrict__ sv, const float* __restrict__ dinv,
                                const int* __restrict__ row_ptr, const int2* __restrict__ pairs,
                                const float* __restrict__ consts, float* __restrict__ out) {
    int tid = threadIdx.x;
    int n = blockIdx.x * 32 + (tid >> 3);
    int l = tid & 7;
    if (n >= N_NODES) return;
    float acc = 0.f;
    int i = row_ptr[n] + l, end = row_ptr[n + 1];
    for (; i < end; i += 8) {
        int2 p = pairs[i];
        acc += __int_as_float(p.y) * sv[p.x];
    }
    acc += __shfl_xor(acc, 1);
    acc += __shfl_xor(acc, 2);
    acc += __shfl_xor(acc, 4);
    if (l == 0) {
        float di = dinv[n];
        float z = acc + di * di * sv[n] + consts[1];
        out[n] = 10.0f / (1.0f + expf(-z));
    }
}

extern "C" void kernel_launch(void* const* d_in, const int* in_sizes, int n_in,
                              void* d_out, int out_size, void* d_ws, size_t ws_size,
                              hipStream_t stream) {
    const float* x  = (const float*)d_in[0];
    const int*   ei = (const int*)d_in[1];
    const float* ew = (const float*)d_in[2];
    const float* W1 = (const float*)d_in[3];
    const float* b1 = (const float*)d_in[4];
    const float* W2 = (const float*)d_in[5];
    const float* b2 = (const float*)d_in[6];
    const float* Wf = (const float*)d_in[7];
    const float* bf = (const float*)d_in[8];
    const int* srcv = ei;
    const int* dstv = ei + N_EDGES;
    float* out = (float*)d_out;

    char* p = (char*)d_ws;
    auto alloc = [&](size_t bytes) { void* r = (void*)p; p += (bytes + 255) & ~(size_t)255; return r; };
    u64*   degcnt = (u64*)alloc((size_t)N_NODES * 8);
    float* dinv   = (float*)alloc(N_NODES * 4);
    int*   rowp   = (int*)alloc((N_NODES + 1) * 4);
    int*   bsum   = (int*)alloc(256 * 4);
    int*   epos   = (int*)alloc((size_t)N_EDGES * 4);
    int2*  pairs  = (int2*)alloc((size_t)N_EDGES * 8);
    float* v      = (float*)alloc(D * 4);
    float* consts = (float*)alloc(2 * 4);
    float* tv     = (float*)alloc(N_NODES * 4);
    float* sv     = (float*)alloc(N_NODES * 4);

    const int NB = (N_NODES + 255) / 256;   // 196
    const int EB = (N_EDGES + 255) / 256;   // 1954

    hipMemsetAsync(degcnt, 0, (size_t)N_NODES * 8, stream);

    // collapse weights: v = W1@(W2@Wf), c1, c0
    precompute_kernel<<<1, 128, 0, stream>>>(W1, W2, b1, b2, Wf, bf, v, consts);
    // t = x @ v (independent of CSR build)
    gemv_kernel<<<N_NODES / 4, 256, 0, stream>>>(x, v, tv);

    // one packed atomic per edge; returned count = CSR slot
    pass1_kernel<<<EB, 256, 0, stream>>>(dstv, ew, degcnt, epos);
    // scan counts -> rowp, unpack deg -> dinv
    scan1_kernel<<<NB, 256, 0, stream>>>(degcnt, dinv, rowp, bsum);
    scan2_kernel<<<1, 256, 0, stream>>>(bsum, NB);
    scan3_kernel<<<NB, 256, 0, stream>>>(rowp, bsum);
    // atomic-free CSR fill with precomputed norms
    fill_kernel<<<EB, 256, 0, stream>>>(srcv, dstv, ew, dinv, rowp, epos, pairs);

    // two scalar aggregations: s = A t + c1 ; out = sigmoid(A s + c0) * 10
    gather_s_kernel<<<(N_NODES + 31) / 32, 256, 0, stream>>>(tv, dinv, rowp, pairs, consts, sv);
    gather_z_kernel<<<(N_NODES + 31) / 32, 256, 0, stream>>>(sv, dinv, rowp, pairs, consts, out);
}